// Round 4
// baseline (373.555 us; speedup 1.0000x reference)
//
#include <hip/hip_runtime.h>

#define BB 2
#define HH 16
#define SS 2048
#define DD 64
#define QT 64
#define KT 64
#define LP 72   // padded LDS row stride in halfs (144 B -> 2-way conflicts only)

using bf16x8 = __attribute__((ext_vector_type(8))) short;
using half8  = __attribute__((ext_vector_type(8))) _Float16;
using f32x4  = __attribute__((ext_vector_type(4))) float;

__device__ __forceinline__ unsigned rotl32(unsigned x, int r) {
  return (x << r) | (x >> (32 - r));
}

// JAX threefry2x32, key (0,42), partitionable: input (0, i), bits = out0^out1.
// keep ⟺ (bitcast((bits>>9)|0x3f800000)-1.0f) < 0.9f ⟺ bits < 0xE6666600
// (exact: f-1 is Sterbenz-exact; threshold = 0x733333<<9). Verified passing r2/r3.
__device__ __forceinline__ bool keep_mask(unsigned i) {
  const unsigned ks1 = 42u;
  const unsigned ks2 = 0x1BD11BDAu ^ 42u;
  unsigned x0 = 0u;
  unsigned x1 = i + ks1;
  x0 += x1; x1 = rotl32(x1, 13); x1 ^= x0;
  x0 += x1; x1 = rotl32(x1, 15); x1 ^= x0;
  x0 += x1; x1 = rotl32(x1, 26); x1 ^= x0;
  x0 += x1; x1 = rotl32(x1,  6); x1 ^= x0;
  x0 += ks1; x1 += ks2 + 1u;
  x0 += x1; x1 = rotl32(x1, 17); x1 ^= x0;
  x0 += x1; x1 = rotl32(x1, 29); x1 ^= x0;
  x0 += x1; x1 = rotl32(x1, 16); x1 ^= x0;
  x0 += x1; x1 = rotl32(x1, 24); x1 ^= x0;
  x0 += ks2; x1 += 2u;
  x0 += x1; x1 = rotl32(x1, 13); x1 ^= x0;
  x0 += x1; x1 = rotl32(x1, 15); x1 ^= x0;
  x0 += x1; x1 = rotl32(x1, 26); x1 ^= x0;
  x0 += x1; x1 = rotl32(x1,  6); x1 ^= x0;
  x1 += ks1 + 3u;
  x0 += x1; x1 = rotl32(x1, 17); x1 ^= x0;
  x0 += x1; x1 = rotl32(x1, 29); x1 ^= x0;
  x0 += x1; x1 = rotl32(x1, 16); x1 ^= x0;
  x0 += x1; x1 = rotl32(x1, 24); x1 ^= x0;
  x0 += ks1; x1 += ks2 + 4u;
  x0 += x1; x1 = rotl32(x1, 13); x1 ^= x0;
  x0 += x1; x1 = rotl32(x1, 15); x1 ^= x0;
  x0 += x1; x1 = rotl32(x1, 26); x1 ^= x0;
  x0 += x1; x1 = rotl32(x1,  6); x1 ^= x0;
  x0 += ks2; x1 += 5u;
  return (x0 ^ x1) < 0xE6666600u;
}

// grid (32, 32): one block per (64-q tile, b*H+h). 4 waves; wave w owns
// q-rows [16w,16w+16). Lane: l15 = l&15, hi4 = l>>4.
// MFMA 16x16x32 frags: A row=l15,k=hi4*8+j; B col=l15,k=hi4*8+j;
// D col=l15, row=hi4*4+reg (m89-verified).
// LDS 36.9 KB -> 4 blocks/CU; grid 1024 = exactly 4 per CU (no tail).
__global__ __launch_bounds__(256, 4)
void fused_attn_mfma(const float* __restrict__ Qg, const float* __restrict__ Kg,
                     const float* __restrict__ Vg, float* __restrict__ Og) {
  __shared__ __attribute__((aligned(16))) unsigned short Ks_hi[KT][LP];
  __shared__ __attribute__((aligned(16))) unsigned short Ks_lo[KT][LP];
  __shared__ __attribute__((aligned(16))) _Float16 Vt[DD][LP];  // [d][k] fp16
  __shared__ __attribute__((aligned(16))) _Float16 Ps[QT][LP];

  const int t   = threadIdx.x;
  const int w   = t >> 6;
  const int l   = t & 63;
  const int l15 = l & 15;
  const int hi4 = l >> 4;

  const int qt0 = blockIdx.x * QT;
  const int bh  = blockIdx.y;
  const int b   = bh >> 4, h = bh & 15;

  auto gidx = [&](int s) { return (((size_t)b * SS + s) * HH + h) * DD; };

  // ---- Q A-fragments in registers (bf16 hi/lo), rows = qt0+16w+l15 ----
  bf16x8 qh[2], ql[2];
  {
    const float* qp = Qg + gidx(qt0 + 16 * w + l15) + hi4 * 8;
    #pragma unroll
    for (int c = 0; c < 2; ++c) {
      float f[8];
      *(float4*)&f[0] = *(const float4*)(qp + c * 32);
      *(float4*)&f[4] = *(const float4*)(qp + c * 32 + 4);
      #pragma unroll
      for (int j = 0; j < 8; ++j) {
        unsigned u = __float_as_uint(f[j]);
        qh[c][j] = (short)(u >> 16);
        float lo = f[j] - __uint_as_float(u & 0xFFFF0000u);
        ql[c][j] = (short)(__float_as_uint(lo) >> 16);
      }
    }
  }

  f32x4 o[4];
  float mrow[4], lrow[4];
  #pragma unroll
  for (int i = 0; i < 4; ++i) { o[i] = (f32x4){0.f,0.f,0.f,0.f}; mrow[i] = -1e30f; lrow[i] = 0.f; }

  // dropout flat-index base for this lane's D-layout rows
  const unsigned fb = ((unsigned)bh * SS + (unsigned)(qt0 + 16 * w + hi4 * 4)) * SS + (unsigned)l15;

  // rolling staging pointers (stride per kt tile: KT rows of HH*DD floats)
  const int rK = t >> 2, cK = (t & 3) * 16;   // K: 4 thr/row, 16 floats each
  const int rV = t & 63, cV = (t >> 6) * 16;  // V: 1 thr/row-quarter (transpose write)
  const float* kp = Kg + gidx(rK) + cK;
  const float* vp = Vg + gidx(rV) + cV;
  const size_t kstride = (size_t)KT * HH * DD;

  for (int kt = 0; kt < SS / KT; ++kt, kp += kstride, vp += kstride) {
    __syncthreads();  // prev iter done reading Ks/Vt/Ps

    // ---- stage K tile as bf16 hi/lo [k][d] ----
    {
      unsigned short khs[16], kls[16];
      #pragma unroll
      for (int u4 = 0; u4 < 4; ++u4) {
        float4 kv = *(const float4*)(kp + u4 * 4);
        float ff[4] = {kv.x, kv.y, kv.z, kv.w};
        #pragma unroll
        for (int j = 0; j < 4; ++j) {
          unsigned u = __float_as_uint(ff[j]);
          khs[u4 * 4 + j] = (unsigned short)(u >> 16);
          float lo = ff[j] - __uint_as_float(u & 0xFFFF0000u);
          kls[u4 * 4 + j] = (unsigned short)(__float_as_uint(lo) >> 16);
        }
      }
      *(bf16x8*)&Ks_hi[rK][cK]     = *(bf16x8*)&khs[0];
      *(bf16x8*)&Ks_hi[rK][cK + 8] = *(bf16x8*)&khs[8];
      *(bf16x8*)&Ks_lo[rK][cK]     = *(bf16x8*)&kls[0];
      *(bf16x8*)&Ks_lo[rK][cK + 8] = *(bf16x8*)&kls[8];
    }
    // ---- stage V transposed as fp16 [d][k] ----
    {
      #pragma unroll
      for (int u4 = 0; u4 < 4; ++u4) {
        float4 vv = *(const float4*)(vp + u4 * 4);
        float ff[4] = {vv.x, vv.y, vv.z, vv.w};
        #pragma unroll
        for (int j = 0; j < 4; ++j)
          Vt[cV + u4 * 4 + j][rV] = (_Float16)ff[j];
      }
    }
    __syncthreads();

    // ---- QK^T via MFMA, 3-term bf16 split ----
    f32x4 s4[4];
    #pragma unroll
    for (int k4 = 0; k4 < 4; ++k4) {
      f32x4 a = (f32x4){0.f,0.f,0.f,0.f};
      #pragma unroll
      for (int c = 0; c < 2; ++c) {
        bf16x8 kh = *(const bf16x8*)&Ks_hi[k4 * 16 + l15][c * 32 + hi4 * 8];
        bf16x8 kl = *(const bf16x8*)&Ks_lo[k4 * 16 + l15][c * 32 + hi4 * 8];
        a = __builtin_amdgcn_mfma_f32_16x16x32_bf16(qh[c], kh, a, 0, 0, 0);
        a = __builtin_amdgcn_mfma_f32_16x16x32_bf16(qh[c], kl, a, 0, 0, 0);
        a = __builtin_amdgcn_mfma_f32_16x16x32_bf16(ql[c], kh, a, 0, 0, 0);
      }
      s4[k4] = a;
    }

    // ---- threefry keep bits (VALU hides shuffle latency below) ----
    unsigned kmask = 0;
    {
      const unsigned ib = fb + (unsigned)(kt * KT);
      #pragma unroll
      for (int r4 = 0; r4 < 4; ++r4)
        #pragma unroll
        for (int k4 = 0; k4 < 4; ++k4)
          kmask |= (keep_mask(ib + (unsigned)(r4 * SS + k4 * 16)) ? 1u : 0u) << (r4 * 4 + k4);
    }

    // ---- online softmax per owned q-row; dropped fp16 P to LDS ----
    float rfac[4];
    #pragma unroll
    for (int r4 = 0; r4 < 4; ++r4) {
      float tm = fmaxf(fmaxf(s4[0][r4], s4[1][r4]), fmaxf(s4[2][r4], s4[3][r4]));
      #pragma unroll
      for (int off = 1; off < 16; off <<= 1)
        tm = fmaxf(tm, __shfl_xor(tm, off, 64));
      tm *= 0.125f;
      const float mn = fmaxf(mrow[r4], tm);
      const float rr = __expf(mrow[r4] - mn);
      float p[4], ps = 0.f;
      #pragma unroll
      for (int k4 = 0; k4 < 4; ++k4) {
        p[k4] = __expf(fmaf(s4[k4][r4], 0.125f, -mn));
        ps += p[k4];
      }
      #pragma unroll
      for (int off = 1; off < 16; off <<= 1)
        ps += __shfl_xor(ps, off, 64);
      lrow[r4] = lrow[r4] * rr + ps;   // denominator: un-dropped sum
      mrow[r4] = mn;
      rfac[r4] = rr;
      #pragma unroll
      for (int k4 = 0; k4 < 4; ++k4) {
        _Float16 ph = ((kmask >> (r4 * 4 + k4)) & 1u) ? (_Float16)p[k4] : (_Float16)0.f;
        Ps[16 * w + hi4 * 4 + r4][k4 * 16 + l15] = ph;
      }
    }
    __syncthreads();  // P visible for A-frag reads

    // ---- PV via MFMA: P(fp16) x V(fp16), fp32 accumulate ----
    half8 pa[2];
    #pragma unroll
    for (int c = 0; c < 2; ++c)
      pa[c] = *(const half8*)&Ps[16 * w + l15][c * 32 + hi4 * 8];
    #pragma unroll
    for (int dt = 0; dt < 4; ++dt) {
      f32x4 a = o[dt];
      #pragma unroll
      for (int i = 0; i < 4; ++i) a[i] *= rfac[i];
      #pragma unroll
      for (int c = 0; c < 2; ++c) {
        half8 vh = *(const half8*)&Vt[dt * 16 + l15][c * 32 + hi4 * 8];
        a = __builtin_amdgcn_mfma_f32_16x16x32_f16(pa[c], vh, a, 0, 0, 0);
      }
      o[dt] = a;
    }
  }

  // ---- epilogue: /(l * 0.9), write [B,H,S,D] ----
  #pragma unroll
  for (int r4 = 0; r4 < 4; ++r4) {
    const float inv = 1.0f / (lrow[r4] * 0.9f);
    const size_t ob = ((size_t)bh * SS + (qt0 + 16 * w + hi4 * 4 + r4)) * DD + l15;
    #pragma unroll
    for (int dt = 0; dt < 4; ++dt)
      Og[ob + dt * 16] = o[dt][r4] * inv;
  }
}

extern "C" void kernel_launch(void* const* d_in, const int* in_sizes, int n_in,
                              void* d_out, int out_size, void* d_ws, size_t ws_size,
                              hipStream_t stream) {
  const float* Q = (const float*)d_in[0];
  const float* K = (const float*)d_in[1];
  const float* V = (const float*)d_in[2];
  float* O = (float*)d_out;
  dim3 grid(SS / QT, BB * HH);
  fused_attn_mfma<<<grid, dim3(256), 0, stream>>>(Q, K, V, O);
}

// Round 5
// 331.198 us; speedup vs baseline: 1.1279x; 1.1279x over previous
//
#include <hip/hip_runtime.h>

#define BB 2
#define HH 16
#define SS 2048
#define DD 64
#define QT 64
#define KT 64
#define LP 72   // padded LDS row stride in halfs (144 B -> 2-way conflicts only)

using bf16x8 = __attribute__((ext_vector_type(8))) short;
using half8  = __attribute__((ext_vector_type(8))) _Float16;
using f32x4  = __attribute__((ext_vector_type(4))) float;

__device__ __forceinline__ unsigned rotl32(unsigned x, int r) {
  return (x << r) | (x >> (32 - r));
}

// JAX threefry2x32, key (0,42), partitionable: input (0, i), bits = out0^out1.
// keep ⟺ (bitcast((bits>>9)|0x3f800000)-1.0f) < 0.9f ⟺ bits < 0xE6666600
// (exact: f-1 is Sterbenz-exact; threshold = 0x733333<<9). Verified passing r2-r4.
__device__ __forceinline__ bool keep_mask(unsigned i) {
  const unsigned ks1 = 42u;
  const unsigned ks2 = 0x1BD11BDAu ^ 42u;
  unsigned x0 = 0u;
  unsigned x1 = i + ks1;
  x0 += x1; x1 = rotl32(x1, 13); x1 ^= x0;
  x0 += x1; x1 = rotl32(x1, 15); x1 ^= x0;
  x0 += x1; x1 = rotl32(x1, 26); x1 ^= x0;
  x0 += x1; x1 = rotl32(x1,  6); x1 ^= x0;
  x0 += ks1; x1 += ks2 + 1u;
  x0 += x1; x1 = rotl32(x1, 17); x1 ^= x0;
  x0 += x1; x1 = rotl32(x1, 29); x1 ^= x0;
  x0 += x1; x1 = rotl32(x1, 16); x1 ^= x0;
  x0 += x1; x1 = rotl32(x1, 24); x1 ^= x0;
  x0 += ks2; x1 += 2u;
  x0 += x1; x1 = rotl32(x1, 13); x1 ^= x0;
  x0 += x1; x1 = rotl32(x1, 15); x1 ^= x0;
  x0 += x1; x1 = rotl32(x1, 26); x1 ^= x0;
  x0 += x1; x1 = rotl32(x1,  6); x1 ^= x0;
  x1 += ks1 + 3u;
  x0 += x1; x1 = rotl32(x1, 17); x1 ^= x0;
  x0 += x1; x1 = rotl32(x1, 29); x1 ^= x0;
  x0 += x1; x1 = rotl32(x1, 16); x1 ^= x0;
  x0 += x1; x1 = rotl32(x1, 24); x1 ^= x0;
  x0 += ks1; x1 += ks2 + 4u;
  x0 += x1; x1 = rotl32(x1, 13); x1 ^= x0;
  x0 += x1; x1 = rotl32(x1, 15); x1 ^= x0;
  x0 += x1; x1 = rotl32(x1, 26); x1 ^= x0;
  x0 += x1; x1 = rotl32(x1,  6); x1 ^= x0;
  x0 += ks2; x1 += 5u;
  return (x0 ^ x1) < 0xE6666600u;
}

// grid (32, 32): one block per (64-q tile, b*H+h). 4 waves; wave w owns
// q-rows [16w,16w+16). Lane: l15 = l&15, hi4 = l>>4.
// SWAPPED QK^T: mfma(K, Q) -> D[k][q], col=q=l15, row(k-in-tile)=hi4*4+reg.
// Each lane holds a full q-row (16 k's) -> in-register softmax, 2 shuffles/reduce.
// A/B frags share the same lane mapping (row/col=l15, k=hi4*8+j), so K/Q
// fragment reads are identical to the verified r3/r4 kernel.
__global__ __launch_bounds__(256, 4)
void fused_attn_mfma(const float* __restrict__ Qg, const float* __restrict__ Kg,
                     const float* __restrict__ Vg, float* __restrict__ Og) {
  __shared__ __attribute__((aligned(16))) unsigned short Ks_hi[KT][LP];
  __shared__ __attribute__((aligned(16))) unsigned short Ks_lo[KT][LP];
  __shared__ __attribute__((aligned(16))) _Float16 Vt[DD][LP];  // [d][k] fp16
  __shared__ __attribute__((aligned(16))) _Float16 Ps[QT][LP];

  const int t   = threadIdx.x;
  const int w   = t >> 6;
  const int l   = t & 63;
  const int l15 = l & 15;
  const int hi4 = l >> 4;

  const int qt0 = blockIdx.x * QT;
  const int bh  = blockIdx.y;
  const int b   = bh >> 4, h = bh & 15;

  auto gidx = [&](int s) { return (((size_t)b * SS + s) * HH + h) * DD; };

  // ---- Q B-fragments in registers (bf16 hi/lo of 0.125*q; 2^-3 is exact) ----
  bf16x8 qh[2], ql[2];
  {
    const float* qp = Qg + gidx(qt0 + 16 * w + l15) + hi4 * 8;
    #pragma unroll
    for (int c = 0; c < 2; ++c) {
      float f[8];
      *(float4*)&f[0] = *(const float4*)(qp + c * 32);
      *(float4*)&f[4] = *(const float4*)(qp + c * 32 + 4);
      #pragma unroll
      for (int j = 0; j < 8; ++j) {
        float qs = 0.125f * f[j];
        unsigned u = __float_as_uint(qs);
        qh[c][j] = (short)(u >> 16);
        float lo = qs - __uint_as_float(u & 0xFFFF0000u);
        ql[c][j] = (short)(__float_as_uint(lo) >> 16);
      }
    }
  }

  f32x4 o[4];
  #pragma unroll
  for (int i = 0; i < 4; ++i) o[i] = (f32x4){0.f, 0.f, 0.f, 0.f};
  float mrow = -1e30f, lrow = 0.f;

  // dropout flat-index base: this lane's softmax q-row is qt0+16w+l15,
  // k offset within tile starts at hi4*4
  const unsigned fb =
      ((unsigned)bh * SS + (unsigned)(qt0 + 16 * w + l15)) * SS + (unsigned)(hi4 * 4);

  // rolling staging pointers
  const int rK = t >> 2, cK = (t & 3) * 16;
  const int rV = t & 63, cV = (t >> 6) * 16;
  const float* kp = Kg + gidx(rK) + cK;
  const float* vp = Vg + gidx(rV) + cV;
  const size_t kstride = (size_t)KT * HH * DD;

  #pragma unroll 1
  for (int kt = 0; kt < SS / KT; ++kt, kp += kstride, vp += kstride) {
    __syncthreads();  // prev iter done reading Ks/Vt/Ps

    // ---- stage K tile as bf16 hi/lo [k][d] ----
    {
      unsigned short khs[16], kls[16];
      #pragma unroll
      for (int u4 = 0; u4 < 4; ++u4) {
        float4 kv = *(const float4*)(kp + u4 * 4);
        float ff[4] = {kv.x, kv.y, kv.z, kv.w};
        #pragma unroll
        for (int j = 0; j < 4; ++j) {
          unsigned u = __float_as_uint(ff[j]);
          khs[u4 * 4 + j] = (unsigned short)(u >> 16);
          float lo = ff[j] - __uint_as_float(u & 0xFFFF0000u);
          kls[u4 * 4 + j] = (unsigned short)(__float_as_uint(lo) >> 16);
        }
      }
      *(bf16x8*)&Ks_hi[rK][cK]     = *(bf16x8*)&khs[0];
      *(bf16x8*)&Ks_hi[rK][cK + 8] = *(bf16x8*)&khs[8];
      *(bf16x8*)&Ks_lo[rK][cK]     = *(bf16x8*)&kls[0];
      *(bf16x8*)&Ks_lo[rK][cK + 8] = *(bf16x8*)&kls[8];
    }
    // ---- stage V transposed as fp16 [d][k] ----
    {
      #pragma unroll
      for (int u4 = 0; u4 < 4; ++u4) {
        float4 vv = *(const float4*)(vp + u4 * 4);
        float ff[4] = {vv.x, vv.y, vv.z, vv.w};
        #pragma unroll
        for (int j = 0; j < 4; ++j)
          Vt[cV + u4 * 4 + j][rV] = (_Float16)ff[j];
      }
    }
    __syncthreads();

    // ---- swapped QK^T: s4[k4][i] = S[k = kt*64 + k4*16 + hi4*4 + i][q = l15-row]
    f32x4 s4[4];
    #pragma unroll
    for (int k4 = 0; k4 < 4; ++k4) {
      f32x4 a = (f32x4){0.f, 0.f, 0.f, 0.f};
      #pragma unroll
      for (int c = 0; c < 2; ++c) {
        bf16x8 kh = *(const bf16x8*)&Ks_hi[k4 * 16 + l15][c * 32 + hi4 * 8];
        bf16x8 kl = *(const bf16x8*)&Ks_lo[k4 * 16 + l15][c * 32 + hi4 * 8];
        a = __builtin_amdgcn_mfma_f32_16x16x32_bf16(kh, qh[c], a, 0, 0, 0);
        a = __builtin_amdgcn_mfma_f32_16x16x32_bf16(kh, ql[c], a, 0, 0, 0);
        a = __builtin_amdgcn_mfma_f32_16x16x32_bf16(kl, qh[c], a, 0, 0, 0);
      }
      s4[k4] = a;
    }

    // ---- threefry keep bits (independent VALU, hides shuffle latency) ----
    unsigned kmaskv = 0;
    {
      const unsigned ib = fb + (unsigned)(kt * KT);
      #pragma unroll
      for (int k4 = 0; k4 < 4; ++k4)
        #pragma unroll
        for (int r = 0; r < 4; ++r)
          kmaskv |= (keep_mask(ib + (unsigned)(k4 * 16 + r)) ? 1u : 0u) << (k4 * 4 + r);
    }

    // ---- in-register online softmax (one q-row per lane) ----
    float mx01 = fmaxf(fmaxf(s4[0][0], s4[0][1]), fmaxf(s4[0][2], s4[0][3]));
    float mx23 = fmaxf(fmaxf(s4[1][0], s4[1][1]), fmaxf(s4[1][2], s4[1][3]));
    float mx45 = fmaxf(fmaxf(s4[2][0], s4[2][1]), fmaxf(s4[2][2], s4[2][3]));
    float mx67 = fmaxf(fmaxf(s4[3][0], s4[3][1]), fmaxf(s4[3][2], s4[3][3]));
    float mx = fmaxf(fmaxf(mx01, mx23), fmaxf(mx45, mx67));
    mx = fmaxf(mx, __shfl_xor(mx, 16, 64));
    mx = fmaxf(mx, __shfl_xor(mx, 32, 64));
    const float mn = fmaxf(mrow, mx);
    const bool grew = !__all(mn == mrow);
    const float rr = __expf(mrow - mn);
    // exp in place; pairwise sum tree
    float ps0 = 0.f, ps1 = 0.f, ps2 = 0.f, ps3 = 0.f;
    #pragma unroll
    for (int k4 = 0; k4 < 4; ++k4) {
      s4[k4][0] = __expf(s4[k4][0] - mn);
      s4[k4][1] = __expf(s4[k4][1] - mn);
      s4[k4][2] = __expf(s4[k4][2] - mn);
      s4[k4][3] = __expf(s4[k4][3] - mn);
    }
    ps0 = (s4[0][0] + s4[0][1]) + (s4[0][2] + s4[0][3]);
    ps1 = (s4[1][0] + s4[1][1]) + (s4[1][2] + s4[1][3]);
    ps2 = (s4[2][0] + s4[2][1]) + (s4[2][2] + s4[2][3]);
    ps3 = (s4[3][0] + s4[3][1]) + (s4[3][2] + s4[3][3]);
    float ps = (ps0 + ps1) + (ps2 + ps3);
    ps += __shfl_xor(ps, 16, 64);
    ps += __shfl_xor(ps, 32, 64);
    lrow = lrow * rr + ps;   // denominator: un-dropped sum
    mrow = mn;

    // ---- dropout-mask and store P (4x ds_write_b64) ----
    #pragma unroll
    for (int k4 = 0; k4 < 4; ++k4) {
      union { uint2 u2; _Float16 hh[4]; } pk;
      #pragma unroll
      for (int r = 0; r < 4; ++r)
        pk.hh[r] = ((kmaskv >> (k4 * 4 + r)) & 1u) ? (_Float16)s4[k4][r] : (_Float16)0.f;
      *(uint2*)&Ps[16 * w + l15][k4 * 16 + hi4 * 4] = pk.u2;
    }
    __syncthreads();  // P visible for A-frag reads

    // ---- PV via MFMA: P(fp16) x V(fp16), fp32 accumulate ----
    half8 pa[2];
    #pragma unroll
    for (int c = 0; c < 2; ++c)
      pa[c] = *(const half8*)&Ps[16 * w + l15][c * 32 + hi4 * 8];
    if (grew) {   // rescale acc by rr of the accumulator's q-rows (hi4*4+i)
      float rfs[4];
      #pragma unroll
      for (int r = 0; r < 4; ++r) rfs[r] = __shfl(rr, hi4 * 4 + r, 64);
      #pragma unroll
      for (int dt = 0; dt < 4; ++dt)
        #pragma unroll
        for (int i = 0; i < 4; ++i) o[dt][i] *= rfs[i];
    }
    #pragma unroll
    for (int dt = 0; dt < 4; ++dt) {
      f32x4 a = o[dt];
      #pragma unroll
      for (int c = 0; c < 2; ++c) {
        half8 vh = *(const half8*)&Vt[dt * 16 + l15][c * 32 + hi4 * 8];
        a = __builtin_amdgcn_mfma_f32_16x16x32_f16(pa[c], vh, a, 0, 0, 0);
      }
      o[dt] = a;
    }
  }

  // ---- epilogue: gather l for accumulator rows, /(l*0.9), write [B,H,S,D] ----
  float lr[4];
  #pragma unroll
  for (int r = 0; r < 4; ++r) lr[r] = __shfl(lrow, hi4 * 4 + r, 64);
  #pragma unroll
  for (int r4 = 0; r4 < 4; ++r4) {
    const float inv = 1.0f / (lr[r4] * 0.9f);
    const size_t ob = ((size_t)bh * SS + (qt0 + 16 * w + hi4 * 4 + r4)) * DD + l15;
    #pragma unroll
    for (int dt = 0; dt < 4; ++dt)
      Og[ob + dt * 16] = o[dt][r4] * inv;
  }
}

extern "C" void kernel_launch(void* const* d_in, const int* in_sizes, int n_in,
                              void* d_out, int out_size, void* d_ws, size_t ws_size,
                              hipStream_t stream) {
  const float* Q = (const float*)d_in[0];
  const float* K = (const float*)d_in[1];
  const float* V = (const float*)d_in[2];
  float* O = (float*)d_out;
  dim3 grid(SS / QT, BB * HH);
  fused_attn_mfma<<<grid, dim3(256), 0, stream>>>(Q, K, V, O);
}

// Round 6
// 327.140 us; speedup vs baseline: 1.1419x; 1.0124x over previous
//
#include <hip/hip_runtime.h>

#define BB 2
#define HH 16
#define SS 2048
#define DD 64
#define QT 64
#define KT 64
#define LP 72   // padded LDS row stride in halfs (144 B -> 2-way conflicts only)

using bf16x8 = __attribute__((ext_vector_type(8))) short;
using half8  = __attribute__((ext_vector_type(8))) _Float16;
using f32x4  = __attribute__((ext_vector_type(4))) float;

// JAX threefry2x32, key (0,42), partitionable: input (0, i), bits = out0^out1.
// keep ⟺ (bitcast((bits>>9)|0x3f800000)-1.0f) < 0.9f ⟺ bits < 0xE6666600
// (exact: f-1 is Sterbenz-exact; threshold = 0x733333<<9). Key schedule
// byte-identical to the r2-r5 verified version; rotates forced to
// v_alignbit_b32 via __builtin_rotateleft32.
__device__ __forceinline__ unsigned tf_bits(unsigned i) {
  const unsigned ks1 = 42u;
  const unsigned ks2 = 0x1BD11BDAu ^ 42u;
  unsigned x0 = 0u;
  unsigned x1 = i + ks1;
#define TF_R(r) { x0 += x1; x1 = __builtin_rotateleft32(x1, r) ^ x0; }
  TF_R(13) TF_R(15) TF_R(26) TF_R(6)
  x0 += ks1; x1 += ks2 + 1u;
  TF_R(17) TF_R(29) TF_R(16) TF_R(24)
  x0 += ks2; x1 += 2u;                 // ks0 + 2
  TF_R(13) TF_R(15) TF_R(26) TF_R(6)
  /* x0 += ks0 (=0) */ x1 += ks1 + 3u;
  TF_R(17) TF_R(29) TF_R(16) TF_R(24)
  x0 += ks1; x1 += ks2 + 4u;
  TF_R(13) TF_R(15) TF_R(26) TF_R(6)
  x0 += ks2; x1 += 5u;                 // (ks2, ks0+5)
#undef TF_R
  return x0 ^ x1;
}

// grid (32, 32): one block per (64-q tile, b*H+h). 4 waves; wave w owns
// q-rows [16w,16w+16). Lane: l15 = l&15, hi4 = l>>4.
// SWAPPED QK^T: mfma(K, Q) -> D[k][q], col=q=l15, row(k-in-tile)=hi4*4+reg.
// Each lane holds a full q-row (16 k's) -> in-register softmax, 2 shuffles/reduce.
__global__ __launch_bounds__(256, 4)
void fused_attn_mfma(const float* __restrict__ Qg, const float* __restrict__ Kg,
                     const float* __restrict__ Vg, float* __restrict__ Og) {
  __shared__ __attribute__((aligned(16))) unsigned short Ks_hi[KT][LP];
  __shared__ __attribute__((aligned(16))) unsigned short Ks_lo[KT][LP];
  __shared__ __attribute__((aligned(16))) _Float16 Vt[DD][LP];  // [d][k] fp16
  __shared__ __attribute__((aligned(16))) _Float16 Ps[QT][LP];

  const int t   = threadIdx.x;
  const int w   = t >> 6;
  const int l   = t & 63;
  const int l15 = l & 15;
  const int hi4 = l >> 4;

  const int qt0 = blockIdx.x * QT;
  const int bh  = blockIdx.y;
  const int b   = bh >> 4, h = bh & 15;

  auto gidx = [&](int s) { return (((size_t)b * SS + s) * HH + h) * DD; };

  // ---- Q B-fragments in registers (bf16 hi/lo of 0.125*q; 2^-3 is exact) ----
  bf16x8 qh[2], ql[2];
  {
    const float* qp = Qg + gidx(qt0 + 16 * w + l15) + hi4 * 8;
    #pragma unroll
    for (int c = 0; c < 2; ++c) {
      float f[8];
      *(float4*)&f[0] = *(const float4*)(qp + c * 32);
      *(float4*)&f[4] = *(const float4*)(qp + c * 32 + 4);
      #pragma unroll
      for (int j = 0; j < 8; ++j) {
        float qs = 0.125f * f[j];
        unsigned u = __float_as_uint(qs);
        qh[c][j] = (short)(u >> 16);
        float lo = qs - __uint_as_float(u & 0xFFFF0000u);
        ql[c][j] = (short)(__float_as_uint(lo) >> 16);
      }
    }
  }

  f32x4 o[4];
  #pragma unroll
  for (int i = 0; i < 4; ++i) o[i] = (f32x4){0.f, 0.f, 0.f, 0.f};
  float mrow = -1e30f, lrow = 0.f;

  // dropout flat-index base: this lane's softmax q-row is qt0+16w+l15,
  // k offset within tile starts at hi4*4
  const unsigned fb =
      ((unsigned)bh * SS + (unsigned)(qt0 + 16 * w + l15)) * SS + (unsigned)(hi4 * 4);

  // rolling staging pointers
  const int rK = t >> 2, cK = (t & 3) * 16;
  const int rV = t & 63, cV = (t >> 6) * 16;
  const float* kp = Kg + gidx(rK) + cK;
  const float* vp = Vg + gidx(rV) + cV;
  const size_t kstride = (size_t)KT * HH * DD;

  #pragma unroll 1
  for (int kt = 0; kt < SS / KT; ++kt, kp += kstride, vp += kstride) {
    __syncthreads();  // prev iter done reading Ks/Vt/Ps

    // ---- stage K tile as bf16 hi/lo [k][d] ----
    {
      unsigned short khs[16], kls[16];
      #pragma unroll
      for (int u4 = 0; u4 < 4; ++u4) {
        float4 kv = *(const float4*)(kp + u4 * 4);
        float ff[4] = {kv.x, kv.y, kv.z, kv.w};
        #pragma unroll
        for (int j = 0; j < 4; ++j) {
          unsigned u = __float_as_uint(ff[j]);
          khs[u4 * 4 + j] = (unsigned short)(u >> 16);
          float lo = ff[j] - __uint_as_float(u & 0xFFFF0000u);
          kls[u4 * 4 + j] = (unsigned short)(__float_as_uint(lo) >> 16);
        }
      }
      *(bf16x8*)&Ks_hi[rK][cK]     = *(bf16x8*)&khs[0];
      *(bf16x8*)&Ks_hi[rK][cK + 8] = *(bf16x8*)&khs[8];
      *(bf16x8*)&Ks_lo[rK][cK]     = *(bf16x8*)&kls[0];
      *(bf16x8*)&Ks_lo[rK][cK + 8] = *(bf16x8*)&kls[8];
    }
    // ---- stage V transposed as fp16 [d][k] ----
    {
      #pragma unroll
      for (int u4 = 0; u4 < 4; ++u4) {
        float4 vv = *(const float4*)(vp + u4 * 4);
        float ff[4] = {vv.x, vv.y, vv.z, vv.w};
        #pragma unroll
        for (int j = 0; j < 4; ++j)
          Vt[cV + u4 * 4 + j][rV] = (_Float16)ff[j];
      }
    }
    __syncthreads();

    // ---- swapped QK^T: s4[k4][i] = S[k = kt*64 + k4*16 + hi4*4 + i][q = l15-row]
    f32x4 s4[4];
    #pragma unroll
    for (int k4 = 0; k4 < 4; ++k4) {
      f32x4 a = (f32x4){0.f, 0.f, 0.f, 0.f};
      #pragma unroll
      for (int c = 0; c < 2; ++c) {
        bf16x8 kh = *(const bf16x8*)&Ks_hi[k4 * 16 + l15][c * 32 + hi4 * 8];
        bf16x8 kl = *(const bf16x8*)&Ks_lo[k4 * 16 + l15][c * 32 + hi4 * 8];
        a = __builtin_amdgcn_mfma_f32_16x16x32_bf16(kh, qh[c], a, 0, 0, 0);
        a = __builtin_amdgcn_mfma_f32_16x16x32_bf16(kh, ql[c], a, 0, 0, 0);
        a = __builtin_amdgcn_mfma_f32_16x16x32_bf16(kl, qh[c], a, 0, 0, 0);
      }
      s4[k4] = a;
    }

    // ---- threefry bits in registers (independent VALU, fills MFMA shadow) ----
    unsigned bts[16];
    {
      const unsigned ib = fb + (unsigned)(kt * KT);
      #pragma unroll
      for (int k4 = 0; k4 < 4; ++k4)
        #pragma unroll
        for (int r = 0; r < 4; ++r)
          bts[k4 * 4 + r] = tf_bits(ib + (unsigned)(k4 * 16 + r));
    }

    // ---- in-register online softmax (one q-row per lane) ----
    float mx01 = fmaxf(fmaxf(s4[0][0], s4[0][1]), fmaxf(s4[0][2], s4[0][3]));
    float mx23 = fmaxf(fmaxf(s4[1][0], s4[1][1]), fmaxf(s4[1][2], s4[1][3]));
    float mx45 = fmaxf(fmaxf(s4[2][0], s4[2][1]), fmaxf(s4[2][2], s4[2][3]));
    float mx67 = fmaxf(fmaxf(s4[3][0], s4[3][1]), fmaxf(s4[3][2], s4[3][3]));
    float mx = fmaxf(fmaxf(mx01, mx23), fmaxf(mx45, mx67));
    mx = fmaxf(mx, __shfl_xor(mx, 16, 64));
    mx = fmaxf(mx, __shfl_xor(mx, 32, 64));
    const float mn = fmaxf(mrow, mx);
    const bool grew = !__all(mn == mrow);
    const float rr = __expf(mrow - mn);
    #pragma unroll
    for (int k4 = 0; k4 < 4; ++k4) {
      s4[k4][0] = __expf(s4[k4][0] - mn);
      s4[k4][1] = __expf(s4[k4][1] - mn);
      s4[k4][2] = __expf(s4[k4][2] - mn);
      s4[k4][3] = __expf(s4[k4][3] - mn);
    }
    float ps0 = (s4[0][0] + s4[0][1]) + (s4[0][2] + s4[0][3]);
    float ps1 = (s4[1][0] + s4[1][1]) + (s4[1][2] + s4[1][3]);
    float ps2 = (s4[2][0] + s4[2][1]) + (s4[2][2] + s4[2][3]);
    float ps3 = (s4[3][0] + s4[3][1]) + (s4[3][2] + s4[3][3]);
    float ps = (ps0 + ps1) + (ps2 + ps3);
    ps += __shfl_xor(ps, 16, 64);
    ps += __shfl_xor(ps, 32, 64);
    lrow = lrow * rr + ps;   // denominator: un-dropped sum
    mrow = mn;

    // ---- dropout (cmp+cndmask on f32) and store P (4x ds_write_b64) ----
    #pragma unroll
    for (int k4 = 0; k4 < 4; ++k4) {
      union { uint2 u2; _Float16 hh[4]; } pk;
      #pragma unroll
      for (int r = 0; r < 4; ++r) {
        float pv = (bts[k4 * 4 + r] < 0xE6666600u) ? s4[k4][r] : 0.f;
        pk.hh[r] = (_Float16)pv;
      }
      *(uint2*)&Ps[16 * w + l15][k4 * 16 + hi4 * 4] = pk.u2;
    }
    __syncthreads();  // P visible for A-frag reads

    // ---- PV via MFMA: P(fp16) x V(fp16), fp32 accumulate ----
    half8 pa[2];
    #pragma unroll
    for (int c = 0; c < 2; ++c)
      pa[c] = *(const half8*)&Ps[16 * w + l15][c * 32 + hi4 * 8];
    if (grew) {   // rescale acc by rr of the accumulator's q-rows (hi4*4+i)
      float rfs[4];
      #pragma unroll
      for (int r = 0; r < 4; ++r) rfs[r] = __shfl(rr, hi4 * 4 + r, 64);
      #pragma unroll
      for (int dt = 0; dt < 4; ++dt)
        #pragma unroll
        for (int i = 0; i < 4; ++i) o[dt][i] *= rfs[i];
    }
    #pragma unroll
    for (int dt = 0; dt < 4; ++dt) {
      f32x4 a = o[dt];
      #pragma unroll
      for (int c = 0; c < 2; ++c) {
        half8 vh = *(const half8*)&Vt[dt * 16 + l15][c * 32 + hi4 * 8];
        a = __builtin_amdgcn_mfma_f32_16x16x32_f16(pa[c], vh, a, 0, 0, 0);
      }
      o[dt] = a;
    }
  }

  // ---- epilogue: gather l for accumulator rows, /(l*0.9), write [B,H,S,D] ----
  float lr[4];
  #pragma unroll
  for (int r = 0; r < 4; ++r) lr[r] = __shfl(lrow, hi4 * 4 + r, 64);
  #pragma unroll
  for (int r4 = 0; r4 < 4; ++r4) {
    const float inv = 1.0f / (lr[r4] * 0.9f);
    const size_t ob = ((size_t)bh * SS + (qt0 + 16 * w + hi4 * 4 + r4)) * DD + l15;
    #pragma unroll
    for (int dt = 0; dt < 4; ++dt)
      Og[ob + dt * 16] = o[dt][r4] * inv;
  }
}

extern "C" void kernel_launch(void* const* d_in, const int* in_sizes, int n_in,
                              void* d_out, int out_size, void* d_ws, size_t ws_size,
                              hipStream_t stream) {
  const float* Q = (const float*)d_in[0];
  const float* K = (const float*)d_in[1];
  const float* V = (const float*)d_in[2];
  float* O = (float*)d_out;
  dim3 grid(SS / QT, BB * HH);
  fused_attn_mfma<<<grid, dim3(256), 0, stream>>>(Q, K, V, O);
}

// Round 7
// 311.827 us; speedup vs baseline: 1.1980x; 1.0491x over previous
//
#include <hip/hip_runtime.h>

#define BB 2
#define HH 16
#define SS 2048
#define DD 64
#define QT 64
#define KT 64
#define NKT (SS / KT)
#define LP 72           // Ps padded row stride (halfs)
#define TILE_BYTES 8192 // one 64x64 fp16/bf16 tile
#define WS_KHI 0
#define WS_KLO (32u * 32u * 8192u)
#define WS_VT  (2u * 32u * 32u * 8192u)
#define WS_NEED ((size_t)3 * 32 * 32 * 8192)

using bf16x8 = __attribute__((ext_vector_type(8))) short;
using half8  = __attribute__((ext_vector_type(8))) _Float16;
using f32x4  = __attribute__((ext_vector_type(4))) float;

typedef __attribute__((address_space(3))) unsigned lds_u32;
typedef __attribute__((address_space(1))) unsigned gvm_u32;
#define GLOAD16(gp, lp) \
  __builtin_amdgcn_global_load_lds((gvm_u32*)(gp), (lds_u32*)(lp), 16, 0, 0)

// JAX threefry2x32, key (0,42), partitionable: input (0, i), bits = out0^out1.
// keep ⟺ bits < 0xE6666600 (exact reformulation of u<0.9f). Verified r2-r6.
__device__ __forceinline__ unsigned tf_bits(unsigned i) {
  const unsigned ks1 = 42u;
  const unsigned ks2 = 0x1BD11BDAu ^ 42u;
  unsigned x0 = 0u;
  unsigned x1 = i + ks1;
#define TF_R(r) { x0 += x1; x1 = __builtin_rotateleft32(x1, r) ^ x0; }
  TF_R(13) TF_R(15) TF_R(26) TF_R(6)
  x0 += ks1; x1 += ks2 + 1u;
  TF_R(17) TF_R(29) TF_R(16) TF_R(24)
  x0 += ks2; x1 += 2u;
  TF_R(13) TF_R(15) TF_R(26) TF_R(6)
  x1 += ks1 + 3u;
  TF_R(17) TF_R(29) TF_R(16) TF_R(24)
  x0 += ks1; x1 += ks2 + 4u;
  TF_R(13) TF_R(15) TF_R(26) TF_R(6)
  x0 += ks2; x1 += 5u;
#undef TF_R
  return x0 ^ x1;
}

// ---- prep: K -> bf16 hi/lo tiles, V -> fp16 transposed tiles, all
// stored with chunk ^= (row&7) swizzle so global_load_lds (linear LDS dest)
// + swizzled ds_read_b128 is bank-conflict-free (rule: swizzle source+read).
__global__ __launch_bounds__(256)
void prep_kv(const float* __restrict__ Kg, const float* __restrict__ Vg,
             char* __restrict__ ws) {
  const int g = blockIdx.x * 256 + threadIdx.x;
  if (blockIdx.x < 2048) {
    // K part: g -> ck(3) | row(6) | kt(5) | bh(5)
    const int ck = g & 7, row = (g >> 3) & 63, kt = (g >> 9) & 31, bh = g >> 14;
    const int b = bh >> 4, h = bh & 15;
    const float* src = Kg + (((size_t)b * SS + kt * 64 + row) * HH + h) * DD + ck * 8;
    float f[8];
    *(float4*)&f[0] = ((const float4*)src)[0];
    *(float4*)&f[4] = ((const float4*)src)[1];
    unsigned short hi[8], lo[8];
    #pragma unroll
    for (int j = 0; j < 8; ++j) {
      unsigned u = __float_as_uint(f[j]);
      hi[j] = (unsigned short)(u >> 16);
      float l = f[j] - __uint_as_float(u & 0xFFFF0000u);
      lo[j] = (unsigned short)(__float_as_uint(l) >> 16);
    }
    const size_t toff = (size_t)(bh * NKT + kt) * TILE_BYTES + row * 128 +
                        ((unsigned)(ck ^ (row & 7))) * 16;
    *(uint4*)(ws + WS_KHI + toff) = *(uint4*)hi;
    *(uint4*)(ws + WS_KLO + toff) = *(uint4*)lo;
  } else {
    // V part: g2 -> d(6) | ck(3) | kt(5) | bh(5); out row = d, chunk over k
    const int g2 = g - (1 << 19);
    const int d = g2 & 63, ck = (g2 >> 6) & 7, kt = (g2 >> 9) & 31, bh = g2 >> 14;
    const int b = bh >> 4, h = bh & 15;
    const float* src = Vg + (((size_t)b * SS + kt * 64 + ck * 8) * HH + h) * DD + d;
    _Float16 hv[8];
    #pragma unroll
    for (int j = 0; j < 8; ++j)
      hv[j] = (_Float16)src[(size_t)j * HH * DD];
    const size_t toff = (size_t)(bh * NKT + kt) * TILE_BYTES + d * 128 +
                        ((unsigned)(ck ^ (d & 7))) * 16;
    *(uint4*)(ws + WS_VT + toff) = *(uint4*)hv;
  }
}

// grid (32, 32): one block per (64-q tile, b*H+h). 4 waves; wave w owns
// q-rows [16w,16w+16). SWAPPED QK^T: mfma(K,Q) -> D[k][q]; lane holds a
// full q-row -> in-register softmax. Staging = 6x global_load_lds from
// pre-converted, pre-swizzled ws tiles. 2 barriers/kt (P round-trip is
// same-wave -> no barrier).
__global__ __launch_bounds__(256, 4)
void fused_attn_ws(const float* __restrict__ Qg, const char* __restrict__ ws,
                   float* __restrict__ Og) {
  __shared__ __attribute__((aligned(16))) unsigned short KsHi[4096]; // [64][64]
  __shared__ __attribute__((aligned(16))) unsigned short KsLo[4096];
  __shared__ __attribute__((aligned(16))) _Float16 VtL[4096];        // [d][k]
  __shared__ __attribute__((aligned(16))) _Float16 Ps[QT][LP];

  const int t   = threadIdx.x;
  const int w   = t >> 6;
  const int l   = t & 63;
  const int l15 = l & 15;
  const int hi4 = l >> 4;
  const int e8  = l15 & 7;

  const int qt0 = blockIdx.x * QT;
  const int bh  = blockIdx.y;
  const int b   = bh >> 4, h = bh & 15;

  // ---- Q B-fragments in registers (bf16 hi/lo of 0.125*q; 2^-3 exact) ----
  bf16x8 qh[2], ql[2];
  {
    const float* qp = Qg + (((size_t)b * SS + qt0 + 16 * w + l15) * HH + h) * DD + hi4 * 8;
    #pragma unroll
    for (int c = 0; c < 2; ++c) {
      float f[8];
      *(float4*)&f[0] = *(const float4*)(qp + c * 32);
      *(float4*)&f[4] = *(const float4*)(qp + c * 32 + 4);
      #pragma unroll
      for (int j = 0; j < 8; ++j) {
        float qs = 0.125f * f[j];
        unsigned u = __float_as_uint(qs);
        qh[c][j] = (short)(u >> 16);
        float lo = qs - __uint_as_float(u & 0xFFFF0000u);
        ql[c][j] = (short)(__float_as_uint(lo) >> 16);
      }
    }
  }

  f32x4 o[4];
  #pragma unroll
  for (int i = 0; i < 4; ++i) o[i] = (f32x4){0.f, 0.f, 0.f, 0.f};
  float mrow = -1e30f, lrow = 0.f;

  const unsigned fb =
      ((unsigned)bh * SS + (unsigned)(qt0 + 16 * w + l15)) * SS + (unsigned)(hi4 * 4);

  // rolling per-lane global source pointers (include wave segment + lane*16)
  const size_t tbase = (size_t)(bh * NKT) * TILE_BYTES + 2048 * w + 16 * l;
  const char* khi_p = ws + WS_KHI + tbase;
  const char* klo_p = ws + WS_KLO + tbase;
  const char* vt_p  = ws + WS_VT  + tbase;

  #pragma unroll 1
  for (int kt = 0; kt < NKT; ++kt,
       khi_p += TILE_BYTES, klo_p += TILE_BYTES, vt_p += TILE_BYTES) {
    __syncthreads();  // prev iter done reading KsHi/KsLo/VtL

    // ---- stage: 6x global_load_lds (wave w fills segments 2w, 2w+1) ----
    GLOAD16(khi_p,        &KsHi[1024 * w]);
    GLOAD16(khi_p + 1024, &KsHi[1024 * w + 512]);
    GLOAD16(klo_p,        &KsLo[1024 * w]);
    GLOAD16(klo_p + 1024, &KsLo[1024 * w + 512]);
    GLOAD16(vt_p,         &VtL[1024 * w]);
    GLOAD16(vt_p + 1024,  &VtL[1024 * w + 512]);
    __syncthreads();  // drains vmcnt + barrier

    // ---- swapped QK^T: s4[k4][i] = S[k=kt*64+k4*16+hi4*4+i][q=l15-row] ----
    f32x4 s4[4];
    #pragma unroll
    for (int k4 = 0; k4 < 4; ++k4) {
      f32x4 a = (f32x4){0.f, 0.f, 0.f, 0.f};
      #pragma unroll
      for (int c = 0; c < 2; ++c) {
        const int co = ((((c << 2) + hi4) ^ e8) << 3);
        bf16x8 kh = *(const bf16x8*)&KsHi[(k4 * 16 + l15) * 64 + co];
        bf16x8 kl = *(const bf16x8*)&KsLo[(k4 * 16 + l15) * 64 + co];
        a = __builtin_amdgcn_mfma_f32_16x16x32_bf16(kh, qh[c], a, 0, 0, 0);
        a = __builtin_amdgcn_mfma_f32_16x16x32_bf16(kh, ql[c], a, 0, 0, 0);
        a = __builtin_amdgcn_mfma_f32_16x16x32_bf16(kl, qh[c], a, 0, 0, 0);
      }
      s4[k4] = a;
    }

    // ---- threefry bits (independent VALU, fills MFMA/shuffle shadow) ----
    unsigned bts[16];
    {
      const unsigned ib = fb + (unsigned)(kt * KT);
      #pragma unroll
      for (int k4 = 0; k4 < 4; ++k4)
        #pragma unroll
        for (int r = 0; r < 4; ++r)
          bts[k4 * 4 + r] = tf_bits(ib + (unsigned)(k4 * 16 + r));
    }

    // ---- in-register online softmax (one q-row per lane) ----
    float mx01 = fmaxf(fmaxf(s4[0][0], s4[0][1]), fmaxf(s4[0][2], s4[0][3]));
    float mx23 = fmaxf(fmaxf(s4[1][0], s4[1][1]), fmaxf(s4[1][2], s4[1][3]));
    float mx45 = fmaxf(fmaxf(s4[2][0], s4[2][1]), fmaxf(s4[2][2], s4[2][3]));
    float mx67 = fmaxf(fmaxf(s4[3][0], s4[3][1]), fmaxf(s4[3][2], s4[3][3]));
    float mx = fmaxf(fmaxf(mx01, mx23), fmaxf(mx45, mx67));
    mx = fmaxf(mx, __shfl_xor(mx, 16, 64));
    mx = fmaxf(mx, __shfl_xor(mx, 32, 64));
    const float mn = fmaxf(mrow, mx);
    const bool grew = !__all(mn == mrow);
    const float rr = __expf(mrow - mn);
    #pragma unroll
    for (int k4 = 0; k4 < 4; ++k4) {
      s4[k4][0] = __expf(s4[k4][0] - mn);
      s4[k4][1] = __expf(s4[k4][1] - mn);
      s4[k4][2] = __expf(s4[k4][2] - mn);
      s4[k4][3] = __expf(s4[k4][3] - mn);
    }
    float ps0 = (s4[0][0] + s4[0][1]) + (s4[0][2] + s4[0][3]);
    float ps1 = (s4[1][0] + s4[1][1]) + (s4[1][2] + s4[1][3]);
    float ps2 = (s4[2][0] + s4[2][1]) + (s4[2][2] + s4[2][3]);
    float ps3 = (s4[3][0] + s4[3][1]) + (s4[3][2] + s4[3][3]);
    float ps = (ps0 + ps1) + (ps2 + ps3);
    ps += __shfl_xor(ps, 16, 64);
    ps += __shfl_xor(ps, 32, 64);
    lrow = lrow * rr + ps;   // denominator: un-dropped sum
    mrow = mn;

    // ---- dropout + store P (same-wave rows -> NO barrier needed) ----
    #pragma unroll
    for (int k4 = 0; k4 < 4; ++k4) {
      union { uint2 u2; _Float16 hh[4]; } pk;
      #pragma unroll
      for (int r = 0; r < 4; ++r) {
        float pv = (bts[k4 * 4 + r] < 0xE6666600u) ? s4[k4][r] : 0.f;
        pk.hh[r] = (_Float16)pv;
      }
      *(uint2*)&Ps[16 * w + l15][k4 * 16 + hi4 * 4] = pk.u2;
    }
    // (compiler inserts lgkmcnt wait for the same-wave RAW below)

    // ---- PV via MFMA: P(fp16) x V(fp16), fp32 accumulate ----
    half8 pa[2];
    #pragma unroll
    for (int c = 0; c < 2; ++c)
      pa[c] = *(const half8*)&Ps[16 * w + l15][c * 32 + hi4 * 8];
    if (grew) {
      float rfs[4];
      #pragma unroll
      for (int r = 0; r < 4; ++r) rfs[r] = __shfl(rr, hi4 * 4 + r, 64);
      #pragma unroll
      for (int dt = 0; dt < 4; ++dt)
        #pragma unroll
        for (int i = 0; i < 4; ++i) o[dt][i] *= rfs[i];
    }
    #pragma unroll
    for (int dt = 0; dt < 4; ++dt) {
      f32x4 a = o[dt];
      #pragma unroll
      for (int c = 0; c < 2; ++c) {
        const int co = ((((c << 2) + hi4) ^ e8) << 3);
        half8 vh = *(const half8*)&VtL[(dt * 16 + l15) * 64 + co];
        a = __builtin_amdgcn_mfma_f32_16x16x32_f16(pa[c], vh, a, 0, 0, 0);
      }
      o[dt] = a;
    }
  }

  // ---- epilogue ----
  float lr[4];
  #pragma unroll
  for (int r = 0; r < 4; ++r) lr[r] = __shfl(lrow, hi4 * 4 + r, 64);
  #pragma unroll
  for (int r4 = 0; r4 < 4; ++r4) {
    const float inv = 1.0f / (lr[r4] * 0.9f);
    const size_t ob = ((size_t)bh * SS + (qt0 + 16 * w + hi4 * 4 + r4)) * DD + l15;
    #pragma unroll
    for (int dt = 0; dt < 4; ++dt)
      Og[ob + dt * 16] = o[dt][r4] * inv;
  }
}

// ================= fallback (r6 kernel, used if ws too small) =================
__global__ __launch_bounds__(256, 4)
void fused_attn_fallback(const float* __restrict__ Qg, const float* __restrict__ Kg,
                         const float* __restrict__ Vg, float* __restrict__ Og) {
  __shared__ __attribute__((aligned(16))) unsigned short Ks_hi[KT][LP];
  __shared__ __attribute__((aligned(16))) unsigned short Ks_lo[KT][LP];
  __shared__ __attribute__((aligned(16))) _Float16 Vt[DD][LP];
  __shared__ __attribute__((aligned(16))) _Float16 Ps[QT][LP];

  const int t = threadIdx.x, w = t >> 6, l = t & 63, l15 = l & 15, hi4 = l >> 4;
  const int qt0 = blockIdx.x * QT, bh = blockIdx.y, b = bh >> 4, h = bh & 15;
  auto gidx = [&](int s) { return (((size_t)b * SS + s) * HH + h) * DD; };

  bf16x8 qh[2], ql[2];
  {
    const float* qp = Qg + gidx(qt0 + 16 * w + l15) + hi4 * 8;
    #pragma unroll
    for (int c = 0; c < 2; ++c) {
      float f[8];
      *(float4*)&f[0] = *(const float4*)(qp + c * 32);
      *(float4*)&f[4] = *(const float4*)(qp + c * 32 + 4);
      #pragma unroll
      for (int j = 0; j < 8; ++j) {
        float qs = 0.125f * f[j];
        unsigned u = __float_as_uint(qs);
        qh[c][j] = (short)(u >> 16);
        float lo = qs - __uint_as_float(u & 0xFFFF0000u);
        ql[c][j] = (short)(__float_as_uint(lo) >> 16);
      }
    }
  }
  f32x4 o[4];
  #pragma unroll
  for (int i = 0; i < 4; ++i) o[i] = (f32x4){0.f, 0.f, 0.f, 0.f};
  float mrow = -1e30f, lrow = 0.f;
  const unsigned fb =
      ((unsigned)bh * SS + (unsigned)(qt0 + 16 * w + l15)) * SS + (unsigned)(hi4 * 4);
  const int rK = t >> 2, cK = (t & 3) * 16;
  const int rV = t & 63, cV = (t >> 6) * 16;
  const float* kp = Kg + gidx(rK) + cK;
  const float* vp = Vg + gidx(rV) + cV;
  const size_t kstride = (size_t)KT * HH * DD;

  #pragma unroll 1
  for (int kt = 0; kt < SS / KT; ++kt, kp += kstride, vp += kstride) {
    __syncthreads();
    {
      unsigned short khs[16], kls[16];
      #pragma unroll
      for (int u4 = 0; u4 < 4; ++u4) {
        float4 kv = *(const float4*)(kp + u4 * 4);
        float ff[4] = {kv.x, kv.y, kv.z, kv.w};
        #pragma unroll
        for (int j = 0; j < 4; ++j) {
          unsigned u = __float_as_uint(ff[j]);
          khs[u4 * 4 + j] = (unsigned short)(u >> 16);
          float lo = ff[j] - __uint_as_float(u & 0xFFFF0000u);
          kls[u4 * 4 + j] = (unsigned short)(__float_as_uint(lo) >> 16);
        }
      }
      *(bf16x8*)&Ks_hi[rK][cK]     = *(bf16x8*)&khs[0];
      *(bf16x8*)&Ks_hi[rK][cK + 8] = *(bf16x8*)&khs[8];
      *(bf16x8*)&Ks_lo[rK][cK]     = *(bf16x8*)&kls[0];
      *(bf16x8*)&Ks_lo[rK][cK + 8] = *(bf16x8*)&kls[8];
    }
    {
      #pragma unroll
      for (int u4 = 0; u4 < 4; ++u4) {
        float4 vv = *(const float4*)(vp + u4 * 4);
        float ff[4] = {vv.x, vv.y, vv.z, vv.w};
        #pragma unroll
        for (int j = 0; j < 4; ++j)
          Vt[cV + u4 * 4 + j][rV] = (_Float16)ff[j];
      }
    }
    __syncthreads();

    f32x4 s4[4];
    #pragma unroll
    for (int k4 = 0; k4 < 4; ++k4) {
      f32x4 a = (f32x4){0.f, 0.f, 0.f, 0.f};
      #pragma unroll
      for (int c = 0; c < 2; ++c) {
        bf16x8 kh = *(const bf16x8*)&Ks_hi[k4 * 16 + l15][c * 32 + hi4 * 8];
        bf16x8 kl = *(const bf16x8*)&Ks_lo[k4 * 16 + l15][c * 32 + hi4 * 8];
        a = __builtin_amdgcn_mfma_f32_16x16x32_bf16(kh, qh[c], a, 0, 0, 0);
        a = __builtin_amdgcn_mfma_f32_16x16x32_bf16(kh, ql[c], a, 0, 0, 0);
        a = __builtin_amdgcn_mfma_f32_16x16x32_bf16(kl, qh[c], a, 0, 0, 0);
      }
      s4[k4] = a;
    }
    unsigned bts[16];
    {
      const unsigned ib = fb + (unsigned)(kt * KT);
      #pragma unroll
      for (int k4 = 0; k4 < 4; ++k4)
        #pragma unroll
        for (int r = 0; r < 4; ++r)
          bts[k4 * 4 + r] = tf_bits(ib + (unsigned)(k4 * 16 + r));
    }
    float mx01 = fmaxf(fmaxf(s4[0][0], s4[0][1]), fmaxf(s4[0][2], s4[0][3]));
    float mx23 = fmaxf(fmaxf(s4[1][0], s4[1][1]), fmaxf(s4[1][2], s4[1][3]));
    float mx45 = fmaxf(fmaxf(s4[2][0], s4[2][1]), fmaxf(s4[2][2], s4[2][3]));
    float mx67 = fmaxf(fmaxf(s4[3][0], s4[3][1]), fmaxf(s4[3][2], s4[3][3]));
    float mx = fmaxf(fmaxf(mx01, mx23), fmaxf(mx45, mx67));
    mx = fmaxf(mx, __shfl_xor(mx, 16, 64));
    mx = fmaxf(mx, __shfl_xor(mx, 32, 64));
    const float mn = fmaxf(mrow, mx);
    const bool grew = !__all(mn == mrow);
    const float rr = __expf(mrow - mn);
    #pragma unroll
    for (int k4 = 0; k4 < 4; ++k4) {
      s4[k4][0] = __expf(s4[k4][0] - mn);
      s4[k4][1] = __expf(s4[k4][1] - mn);
      s4[k4][2] = __expf(s4[k4][2] - mn);
      s4[k4][3] = __expf(s4[k4][3] - mn);
    }
    float ps0 = (s4[0][0] + s4[0][1]) + (s4[0][2] + s4[0][3]);
    float ps1 = (s4[1][0] + s4[1][1]) + (s4[1][2] + s4[1][3]);
    float ps2 = (s4[2][0] + s4[2][1]) + (s4[2][2] + s4[2][3]);
    float ps3 = (s4[3][0] + s4[3][1]) + (s4[3][2] + s4[3][3]);
    float ps = (ps0 + ps1) + (ps2 + ps3);
    ps += __shfl_xor(ps, 16, 64);
    ps += __shfl_xor(ps, 32, 64);
    lrow = lrow * rr + ps;
    mrow = mn;
    #pragma unroll
    for (int k4 = 0; k4 < 4; ++k4) {
      union { uint2 u2; _Float16 hh[4]; } pk;
      #pragma unroll
      for (int r = 0; r < 4; ++r) {
        float pv = (bts[k4 * 4 + r] < 0xE6666600u) ? s4[k4][r] : 0.f;
        pk.hh[r] = (_Float16)pv;
      }
      *(uint2*)&Ps[16 * w + l15][k4 * 16 + hi4 * 4] = pk.u2;
    }
    __syncthreads();
    half8 pa[2];
    #pragma unroll
    for (int c = 0; c < 2; ++c)
      pa[c] = *(const half8*)&Ps[16 * w + l15][c * 32 + hi4 * 8];
    if (grew) {
      float rfs[4];
      #pragma unroll
      for (int r = 0; r < 4; ++r) rfs[r] = __shfl(rr, hi4 * 4 + r, 64);
      #pragma unroll
      for (int dt = 0; dt < 4; ++dt)
        #pragma unroll
        for (int i = 0; i < 4; ++i) o[dt][i] *= rfs[i];
    }
    #pragma unroll
    for (int dt = 0; dt < 4; ++dt) {
      f32x4 a = o[dt];
      #pragma unroll
      for (int c = 0; c < 2; ++c) {
        half8 vh = *(const half8*)&Vt[dt * 16 + l15][c * 32 + hi4 * 8];
        a = __builtin_amdgcn_mfma_f32_16x16x32_f16(pa[c], vh, a, 0, 0, 0);
      }
      o[dt] = a;
    }
  }
  float lr[4];
  #pragma unroll
  for (int r = 0; r < 4; ++r) lr[r] = __shfl(lrow, hi4 * 4 + r, 64);
  #pragma unroll
  for (int r4 = 0; r4 < 4; ++r4) {
    const float inv = 1.0f / (lr[r4] * 0.9f);
    const size_t ob = ((size_t)bh * SS + (qt0 + 16 * w + hi4 * 4 + r4)) * DD + l15;
    #pragma unroll
    for (int dt = 0; dt < 4; ++dt)
      Og[ob + dt * 16] = o[dt][r4] * inv;
  }
}

extern "C" void kernel_launch(void* const* d_in, const int* in_sizes, int n_in,
                              void* d_out, int out_size, void* d_ws, size_t ws_size,
                              hipStream_t stream) {
  const float* Q = (const float*)d_in[0];
  const float* K = (const float*)d_in[1];
  const float* V = (const float*)d_in[2];
  float* O = (float*)d_out;
  dim3 grid(SS / QT, BB * HH);
  if (ws_size >= WS_NEED) {
    char* wsp = (char*)d_ws;
    prep_kv<<<4096, 256, 0, stream>>>(K, V, wsp);
    fused_attn_ws<<<grid, dim3(256), 0, stream>>>(Q, wsp, O);
  } else {
    fused_attn_fallback<<<grid, dim3(256), 0, stream>>>(Q, K, V, O);
  }
}

// Round 8
// 309.650 us; speedup vs baseline: 1.2064x; 1.0070x over previous
//
#include <hip/hip_runtime.h>

#define BB 2
#define HH 16
#define SS 2048
#define DD 64
#define QT 64
#define KT 64
#define NKT (SS / KT)
#define LP 72           // Ps padded row stride (halfs)
#define TILE_BYTES 8192 // one 64x64 fp16/bf16 tile
#define WS_KHI 0
#define WS_KLO (32u * 32u * 8192u)
#define WS_VT  (2u * 32u * 32u * 8192u)
#define WS_NEED ((size_t)3 * 32 * 32 * 8192)

using bf16x8 = __attribute__((ext_vector_type(8))) short;
using half8  = __attribute__((ext_vector_type(8))) _Float16;
using f32x4  = __attribute__((ext_vector_type(4))) float;

typedef __attribute__((address_space(3))) unsigned lds_u32;
typedef __attribute__((address_space(1))) unsigned gvm_u32;
#define GLOAD16(gp, lp) \
  __builtin_amdgcn_global_load_lds((gvm_u32*)(gp), (lds_u32*)(lp), 16, 0, 0)

// JAX threefry2x32, key (0,42), partitionable: input (0, i), bits = out0^out1.
// keep ⟺ bits < 0xE6666600 (exact reformulation of u<0.9f). Verified r2-r7.
__device__ __forceinline__ unsigned tf_bits(unsigned i) {
  const unsigned ks1 = 42u;
  const unsigned ks2 = 0x1BD11BDAu ^ 42u;
  unsigned x0 = 0u;
  unsigned x1 = i + ks1;
#define TF_R(r) { x0 += x1; x1 = __builtin_rotateleft32(x1, r) ^ x0; }
  TF_R(13) TF_R(15) TF_R(26) TF_R(6)
  x0 += ks1; x1 += ks2 + 1u;
  TF_R(17) TF_R(29) TF_R(16) TF_R(24)
  x0 += ks2; x1 += 2u;
  TF_R(13) TF_R(15) TF_R(26) TF_R(6)
  x1 += ks1 + 3u;
  TF_R(17) TF_R(29) TF_R(16) TF_R(24)
  x0 += ks1; x1 += ks2 + 4u;
  TF_R(13) TF_R(15) TF_R(26) TF_R(6)
  x0 += ks2; x1 += 5u;
#undef TF_R
  return x0 ^ x1;
}

// ---- prep: K -> bf16 hi/lo tiles, V -> fp16 transposed tiles, all
// stored with chunk ^= (row&7) swizzle so global_load_lds (linear LDS dest)
// + swizzled ds_read_b128 is bank-conflict-free (rule: swizzle source+read).
__global__ __launch_bounds__(256)
void prep_kv(const float* __restrict__ Kg, const float* __restrict__ Vg,
             char* __restrict__ ws) {
  const int g = blockIdx.x * 256 + threadIdx.x;
  if (blockIdx.x < 2048) {
    // K part: g -> ck(3) | row(6) | kt(5) | bh(5)
    const int ck = g & 7, row = (g >> 3) & 63, kt = (g >> 9) & 31, bh = g >> 14;
    const int b = bh >> 4, h = bh & 15;
    const float* src = Kg + (((size_t)b * SS + kt * 64 + row) * HH + h) * DD + ck * 8;
    float f[8];
    *(float4*)&f[0] = ((const float4*)src)[0];
    *(float4*)&f[4] = ((const float4*)src)[1];
    unsigned short hi[8], lo[8];
    #pragma unroll
    for (int j = 0; j < 8; ++j) {
      unsigned u = __float_as_uint(f[j]);
      hi[j] = (unsigned short)(u >> 16);
      float l = f[j] - __uint_as_float(u & 0xFFFF0000u);
      lo[j] = (unsigned short)(__float_as_uint(l) >> 16);
    }
    const size_t toff = (size_t)(bh * NKT + kt) * TILE_BYTES + row * 128 +
                        ((unsigned)(ck ^ (row & 7))) * 16;
    *(uint4*)(ws + WS_KHI + toff) = *(uint4*)hi;
    *(uint4*)(ws + WS_KLO + toff) = *(uint4*)lo;
  } else {
    // V part: g2 -> d(6) | ck(3) | kt(5) | bh(5); out row = d, chunk over k
    const int g2 = g - (1 << 19);
    const int d = g2 & 63, ck = (g2 >> 6) & 7, kt = (g2 >> 9) & 31, bh = g2 >> 14;
    const int b = bh >> 4, h = bh & 15;
    const float* src = Vg + (((size_t)b * SS + kt * 64 + ck * 8) * HH + h) * DD + d;
    _Float16 hv[8];
    #pragma unroll
    for (int j = 0; j < 8; ++j)
      hv[j] = (_Float16)src[(size_t)j * HH * DD];
    const size_t toff = (size_t)(bh * NKT + kt) * TILE_BYTES + d * 128 +
                        ((unsigned)(ck ^ (d & 7))) * 16;
    *(uint4*)(ws + WS_VT + toff) = *(uint4*)hv;
  }
}

// grid (32, 32): one block per (64-q tile, b*H+h). 4 waves; wave w owns
// q-rows [16w,16w+16). SWAPPED QK^T: mfma(K,Q) -> D[k][q]; lane holds a
// full q-row -> in-register softmax. Double-buffered staging (T3-min):
// stage tile kt+1 at top of iter kt, ONE barrier per kt, vmcnt drain
// hidden under ~2700 cyc of compute. LDS 57.2 KB -> 2 blocks/CU.
__global__ __launch_bounds__(256, 2)
void fused_attn_ws(const float* __restrict__ Qg, const char* __restrict__ ws,
                   float* __restrict__ Og) {
  __shared__ __attribute__((aligned(16))) unsigned short KsHi[2][4096];
  __shared__ __attribute__((aligned(16))) unsigned short KsLo[2][4096];
  __shared__ __attribute__((aligned(16))) _Float16 VtL[2][4096];
  __shared__ __attribute__((aligned(16))) _Float16 Ps[QT][LP];

  const int t   = threadIdx.x;
  const int w   = t >> 6;
  const int l   = t & 63;
  const int l15 = l & 15;
  const int hi4 = l >> 4;
  const int e8  = l15 & 7;

  const int qt0 = blockIdx.x * QT;
  const int bh  = blockIdx.y;
  const int b   = bh >> 4, h = bh & 15;

  // ---- Q B-fragments in registers (bf16 hi/lo of 0.125*q; 2^-3 exact) ----
  bf16x8 qh[2], ql[2];
  {
    const float* qp = Qg + (((size_t)b * SS + qt0 + 16 * w + l15) * HH + h) * DD + hi4 * 8;
    #pragma unroll
    for (int c = 0; c < 2; ++c) {
      float f[8];
      *(float4*)&f[0] = *(const float4*)(qp + c * 32);
      *(float4*)&f[4] = *(const float4*)(qp + c * 32 + 4);
      #pragma unroll
      for (int j = 0; j < 8; ++j) {
        float qs = 0.125f * f[j];
        unsigned u = __float_as_uint(qs);
        qh[c][j] = (short)(u >> 16);
        float lo = qs - __uint_as_float(u & 0xFFFF0000u);
        ql[c][j] = (short)(__float_as_uint(lo) >> 16);
      }
    }
  }

  f32x4 o[4];
  #pragma unroll
  for (int i = 0; i < 4; ++i) o[i] = (f32x4){0.f, 0.f, 0.f, 0.f};
  float mrow = -1e30f, lrow = 0.f;

  const unsigned fb =
      ((unsigned)bh * SS + (unsigned)(qt0 + 16 * w + l15)) * SS + (unsigned)(hi4 * 4);

  // rolling per-lane global source pointers (wave segment + lane*16)
  const size_t tbase = (size_t)(bh * NKT) * TILE_BYTES + 2048 * w + 16 * l;
  const char* khi_p = ws + WS_KHI + tbase;
  const char* klo_p = ws + WS_KLO + tbase;
  const char* vt_p  = ws + WS_VT  + tbase;

  // stage next tile into buf; advances rolling pointers
  auto do_stage = [&](int buf) {
    GLOAD16(khi_p,        &KsHi[buf][1024 * w]);
    GLOAD16(khi_p + 1024, &KsHi[buf][1024 * w + 512]);
    GLOAD16(klo_p,        &KsLo[buf][1024 * w]);
    GLOAD16(klo_p + 1024, &KsLo[buf][1024 * w + 512]);
    GLOAD16(vt_p,         &VtL[buf][1024 * w]);
    GLOAD16(vt_p + 1024,  &VtL[buf][1024 * w + 512]);
    khi_p += TILE_BYTES; klo_p += TILE_BYTES; vt_p += TILE_BYTES;
  };

  // full K-tile compute on buf
  auto do_tile = [&](int buf, int kt) {
    const unsigned short* KH = &KsHi[buf][0];
    const unsigned short* KL = &KsLo[buf][0];
    const _Float16*       VT = &VtL[buf][0];

    // ---- swapped QK^T: s4[k4][i] = S[k=kt*64+k4*16+hi4*4+i][q=l15-row] ----
    f32x4 s4[4];
    #pragma unroll
    for (int k4 = 0; k4 < 4; ++k4) {
      f32x4 a = (f32x4){0.f, 0.f, 0.f, 0.f};
      #pragma unroll
      for (int c = 0; c < 2; ++c) {
        const int co = ((((c << 2) + hi4) ^ e8) << 3);
        bf16x8 kh = *(const bf16x8*)&KH[(k4 * 16 + l15) * 64 + co];
        bf16x8 kl = *(const bf16x8*)&KL[(k4 * 16 + l15) * 64 + co];
        a = __builtin_amdgcn_mfma_f32_16x16x32_bf16(kh, qh[c], a, 0, 0, 0);
        a = __builtin_amdgcn_mfma_f32_16x16x32_bf16(kh, ql[c], a, 0, 0, 0);
        a = __builtin_amdgcn_mfma_f32_16x16x32_bf16(kl, qh[c], a, 0, 0, 0);
      }
      s4[k4] = a;
    }

    // ---- threefry bits (independent VALU, fills MFMA/shuffle shadow) ----
    unsigned bts[16];
    {
      const unsigned ib = fb + (unsigned)(kt * KT);
      #pragma unroll
      for (int k4 = 0; k4 < 4; ++k4)
        #pragma unroll
        for (int r = 0; r < 4; ++r)
          bts[k4 * 4 + r] = tf_bits(ib + (unsigned)(k4 * 16 + r));
    }

    // ---- in-register online softmax (one q-row per lane) ----
    float mx01 = fmaxf(fmaxf(s4[0][0], s4[0][1]), fmaxf(s4[0][2], s4[0][3]));
    float mx23 = fmaxf(fmaxf(s4[1][0], s4[1][1]), fmaxf(s4[1][2], s4[1][3]));
    float mx45 = fmaxf(fmaxf(s4[2][0], s4[2][1]), fmaxf(s4[2][2], s4[2][3]));
    float mx67 = fmaxf(fmaxf(s4[3][0], s4[3][1]), fmaxf(s4[3][2], s4[3][3]));
    float mx = fmaxf(fmaxf(mx01, mx23), fmaxf(mx45, mx67));
    mx = fmaxf(mx, __shfl_xor(mx, 16, 64));
    mx = fmaxf(mx, __shfl_xor(mx, 32, 64));
    const float mn = fmaxf(mrow, mx);
    const bool grew = !__all(mn == mrow);
    const float rr = __expf(mrow - mn);
    #pragma unroll
    for (int k4 = 0; k4 < 4; ++k4) {
      s4[k4][0] = __expf(s4[k4][0] - mn);
      s4[k4][1] = __expf(s4[k4][1] - mn);
      s4[k4][2] = __expf(s4[k4][2] - mn);
      s4[k4][3] = __expf(s4[k4][3] - mn);
    }
    float ps0 = (s4[0][0] + s4[0][1]) + (s4[0][2] + s4[0][3]);
    float ps1 = (s4[1][0] + s4[1][1]) + (s4[1][2] + s4[1][3]);
    float ps2 = (s4[2][0] + s4[2][1]) + (s4[2][2] + s4[2][3]);
    float ps3 = (s4[3][0] + s4[3][1]) + (s4[3][2] + s4[3][3]);
    float ps = (ps0 + ps1) + (ps2 + ps3);
    ps += __shfl_xor(ps, 16, 64);
    ps += __shfl_xor(ps, 32, 64);
    lrow = lrow * rr + ps;   // denominator: un-dropped sum
    mrow = mn;

    // ---- dropout + store P (same-wave rows -> no barrier needed) ----
    #pragma unroll
    for (int k4 = 0; k4 < 4; ++k4) {
      union { uint2 u2; _Float16 hh[4]; } pk;
      #pragma unroll
      for (int r = 0; r < 4; ++r) {
        float pv = (bts[k4 * 4 + r] < 0xE6666600u) ? s4[k4][r] : 0.f;
        pk.hh[r] = (_Float16)pv;
      }
      *(uint2*)&Ps[16 * w + l15][k4 * 16 + hi4 * 4] = pk.u2;
    }

    // ---- PV via MFMA: P(fp16) x V(fp16), fp32 accumulate ----
    half8 pa[2];
    #pragma unroll
    for (int c = 0; c < 2; ++c)
      pa[c] = *(const half8*)&Ps[16 * w + l15][c * 32 + hi4 * 8];
    if (grew) {
      float rfs[4];
      #pragma unroll
      for (int r = 0; r < 4; ++r) rfs[r] = __shfl(rr, hi4 * 4 + r, 64);
      #pragma unroll
      for (int dt = 0; dt < 4; ++dt)
        #pragma unroll
        for (int i = 0; i < 4; ++i) o[dt][i] *= rfs[i];
    }
    #pragma unroll
    for (int dt = 0; dt < 4; ++dt) {
      f32x4 a = o[dt];
      #pragma unroll
      for (int c = 0; c < 2; ++c) {
        const int co = ((((c << 2) + hi4) ^ e8) << 3);
        half8 vh = *(const half8*)&VT[(dt * 16 + l15) * 64 + co];
        a = __builtin_amdgcn_mfma_f32_16x16x32_f16(pa[c], vh, a, 0, 0, 0);
      }
      o[dt] = a;
    }
  };

  // ---- software pipeline: 1 barrier/kt, loads always 1 tile ahead ----
  do_stage(0);
  __syncthreads();                 // prologue drain (only exposed wait)
  #pragma unroll 1
  for (int kt = 0; kt < NKT; kt += 2) {
    do_stage(1);                   // stage kt+1 (kt+1 <= 31 always)
    do_tile(0, kt);
    __syncthreads();               // drains stage(kt+1) after ~2700cyc compute
    if (kt + 2 < NKT) do_stage(0); // stage kt+2
    do_tile(1, kt + 1);
    __syncthreads();
  }

  // ---- epilogue ----
  float lr[4];
  #pragma unroll
  for (int r = 0; r < 4; ++r) lr[r] = __shfl(lrow, hi4 * 4 + r, 64);
  #pragma unroll
  for (int r4 = 0; r4 < 4; ++r4) {
    const float inv = 1.0f / (lr[r4] * 0.9f);
    const size_t ob = ((size_t)bh * SS + (qt0 + 16 * w + hi4 * 4 + r4)) * DD + l15;
    #pragma unroll
    for (int dt = 0; dt < 4; ++dt)
      Og[ob + dt * 16] = o[dt][r4] * inv;
  }
}

// ================= fallback (r6 kernel, used if ws too small) =================
__global__ __launch_bounds__(256, 4)
void fused_attn_fallback(const float* __restrict__ Qg, const float* __restrict__ Kg,
                         const float* __restrict__ Vg, float* __restrict__ Og) {
  __shared__ __attribute__((aligned(16))) unsigned short Ks_hi[KT][LP];
  __shared__ __attribute__((aligned(16))) unsigned short Ks_lo[KT][LP];
  __shared__ __attribute__((aligned(16))) _Float16 Vt[DD][LP];
  __shared__ __attribute__((aligned(16))) _Float16 Ps[QT][LP];

  const int t = threadIdx.x, w = t >> 6, l = t & 63, l15 = l & 15, hi4 = l >> 4;
  const int qt0 = blockIdx.x * QT, bh = blockIdx.y, b = bh >> 4, h = bh & 15;
  auto gidx = [&](int s) { return (((size_t)b * SS + s) * HH + h) * DD; };

  bf16x8 qh[2], ql[2];
  {
    const float* qp = Qg + gidx(qt0 + 16 * w + l15) + hi4 * 8;
    #pragma unroll
    for (int c = 0; c < 2; ++c) {
      float f[8];
      *(float4*)&f[0] = *(const float4*)(qp + c * 32);
      *(float4*)&f[4] = *(const float4*)(qp + c * 32 + 4);
      #pragma unroll
      for (int j = 0; j < 8; ++j) {
        float qs = 0.125f * f[j];
        unsigned u = __float_as_uint(qs);
        qh[c][j] = (short)(u >> 16);
        float lo = qs - __uint_as_float(u & 0xFFFF0000u);
        ql[c][j] = (short)(__float_as_uint(lo) >> 16);
      }
    }
  }
  f32x4 o[4];
  #pragma unroll
  for (int i = 0; i < 4; ++i) o[i] = (f32x4){0.f, 0.f, 0.f, 0.f};
  float mrow = -1e30f, lrow = 0.f;
  const unsigned fb =
      ((unsigned)bh * SS + (unsigned)(qt0 + 16 * w + l15)) * SS + (unsigned)(hi4 * 4);
  const int rK = t >> 2, cK = (t & 3) * 16;
  const int rV = t & 63, cV = (t >> 6) * 16;
  const float* kp = Kg + gidx(rK) + cK;
  const float* vp = Vg + gidx(rV) + cV;
  const size_t kstride = (size_t)KT * HH * DD;

  #pragma unroll 1
  for (int kt = 0; kt < SS / KT; ++kt, kp += kstride, vp += kstride) {
    __syncthreads();
    {
      unsigned short khs[16], kls[16];
      #pragma unroll
      for (int u4 = 0; u4 < 4; ++u4) {
        float4 kv = *(const float4*)(kp + u4 * 4);
        float ff[4] = {kv.x, kv.y, kv.z, kv.w};
        #pragma unroll
        for (int j = 0; j < 4; ++j) {
          unsigned u = __float_as_uint(ff[j]);
          khs[u4 * 4 + j] = (unsigned short)(u >> 16);
          float lo = ff[j] - __uint_as_float(u & 0xFFFF0000u);
          kls[u4 * 4 + j] = (unsigned short)(__float_as_uint(lo) >> 16);
        }
      }
      *(bf16x8*)&Ks_hi[rK][cK]     = *(bf16x8*)&khs[0];
      *(bf16x8*)&Ks_hi[rK][cK + 8] = *(bf16x8*)&khs[8];
      *(bf16x8*)&Ks_lo[rK][cK]     = *(bf16x8*)&kls[0];
      *(bf16x8*)&Ks_lo[rK][cK + 8] = *(bf16x8*)&kls[8];
    }
    {
      #pragma unroll
      for (int u4 = 0; u4 < 4; ++u4) {
        float4 vv = *(const float4*)(vp + u4 * 4);
        float ff[4] = {vv.x, vv.y, vv.z, vv.w};
        #pragma unroll
        for (int j = 0; j < 4; ++j)
          Vt[cV + u4 * 4 + j][rV] = (_Float16)ff[j];
      }
    }
    __syncthreads();

    f32x4 s4[4];
    #pragma unroll
    for (int k4 = 0; k4 < 4; ++k4) {
      f32x4 a = (f32x4){0.f, 0.f, 0.f, 0.f};
      #pragma unroll
      for (int c = 0; c < 2; ++c) {
        bf16x8 kh = *(const bf16x8*)&Ks_hi[k4 * 16 + l15][c * 32 + hi4 * 8];
        bf16x8 kl = *(const bf16x8*)&Ks_lo[k4 * 16 + l15][c * 32 + hi4 * 8];
        a = __builtin_amdgcn_mfma_f32_16x16x32_bf16(kh, qh[c], a, 0, 0, 0);
        a = __builtin_amdgcn_mfma_f32_16x16x32_bf16(kh, ql[c], a, 0, 0, 0);
        a = __builtin_amdgcn_mfma_f32_16x16x32_bf16(kl, qh[c], a, 0, 0, 0);
      }
      s4[k4] = a;
    }
    unsigned bts[16];
    {
      const unsigned ib = fb + (unsigned)(kt * KT);
      #pragma unroll
      for (int k4 = 0; k4 < 4; ++k4)
        #pragma unroll
        for (int r = 0; r < 4; ++r)
          bts[k4 * 4 + r] = tf_bits(ib + (unsigned)(k4 * 16 + r));
    }
    float mx01 = fmaxf(fmaxf(s4[0][0], s4[0][1]), fmaxf(s4[0][2], s4[0][3]));
    float mx23 = fmaxf(fmaxf(s4[1][0], s4[1][1]), fmaxf(s4[1][2], s4[1][3]));
    float mx45 = fmaxf(fmaxf(s4[2][0], s4[2][1]), fmaxf(s4[2][2], s4[2][3]));
    float mx67 = fmaxf(fmaxf(s4[3][0], s4[3][1]), fmaxf(s4[3][2], s4[3][3]));
    float mx = fmaxf(fmaxf(mx01, mx23), fmaxf(mx45, mx67));
    mx = fmaxf(mx, __shfl_xor(mx, 16, 64));
    mx = fmaxf(mx, __shfl_xor(mx, 32, 64));
    const float mn = fmaxf(mrow, mx);
    const bool grew = !__all(mn == mrow);
    const float rr = __expf(mrow - mn);
    #pragma unroll
    for (int k4 = 0; k4 < 4; ++k4) {
      s4[k4][0] = __expf(s4[k4][0] - mn);
      s4[k4][1] = __expf(s4[k4][1] - mn);
      s4[k4][2] = __expf(s4[k4][2] - mn);
      s4[k4][3] = __expf(s4[k4][3] - mn);
    }
    float ps0 = (s4[0][0] + s4[0][1]) + (s4[0][2] + s4[0][3]);
    float ps1 = (s4[1][0] + s4[1][1]) + (s4[1][2] + s4[1][3]);
    float ps2 = (s4[2][0] + s4[2][1]) + (s4[2][2] + s4[2][3]);
    float ps3 = (s4[3][0] + s4[3][1]) + (s4[3][2] + s4[3][3]);
    float ps = (ps0 + ps1) + (ps2 + ps3);
    ps += __shfl_xor(ps, 16, 64);
    ps += __shfl_xor(ps, 32, 64);
    lrow = lrow * rr + ps;
    mrow = mn;
    #pragma unroll
    for (int k4 = 0; k4 < 4; ++k4) {
      union { uint2 u2; _Float16 hh[4]; } pk;
      #pragma unroll
      for (int r = 0; r < 4; ++r) {
        float pv = (bts[k4 * 4 + r] < 0xE6666600u) ? s4[k4][r] : 0.f;
        pk.hh[r] = (_Float16)pv;
      }
      *(uint2*)&Ps[16 * w + l15][k4 * 16 + hi4 * 4] = pk.u2;
    }
    __syncthreads();
    half8 pa[2];
    #pragma unroll
    for (int c = 0; c < 2; ++c)
      pa[c] = *(const half8*)&Ps[16 * w + l15][c * 32 + hi4 * 8];
    if (grew) {
      float rfs[4];
      #pragma unroll
      for (int r = 0; r < 4; ++r) rfs[r] = __shfl(rr, hi4 * 4 + r, 64);
      #pragma unroll
      for (int dt = 0; dt < 4; ++dt)
        #pragma unroll
        for (int i = 0; i < 4; ++i) o[dt][i] *= rfs[i];
    }
    #pragma unroll
    for (int dt = 0; dt < 4; ++dt) {
      f32x4 a = o[dt];
      #pragma unroll
      for (int c = 0; c < 2; ++c) {
        half8 vh = *(const half8*)&Vt[dt * 16 + l15][c * 32 + hi4 * 8];
        a = __builtin_amdgcn_mfma_f32_16x16x32_f16(pa[c], vh, a, 0, 0, 0);
      }
      o[dt] = a;
    }
  }
  float lr[4];
  #pragma unroll
  for (int r = 0; r < 4; ++r) lr[r] = __shfl(lrow, hi4 * 4 + r, 64);
  #pragma unroll
  for (int r4 = 0; r4 < 4; ++r4) {
    const float inv = 1.0f / (lr[r4] * 0.9f);
    const size_t ob = ((size_t)bh * SS + (qt0 + 16 * w + hi4 * 4 + r4)) * DD + l15;
    #pragma unroll
    for (int dt = 0; dt < 4; ++dt)
      Og[ob + dt * 16] = o[dt][r4] * inv;
  }
}

extern "C" void kernel_launch(void* const* d_in, const int* in_sizes, int n_in,
                              void* d_out, int out_size, void* d_ws, size_t ws_size,
                              hipStream_t stream) {
  const float* Q = (const float*)d_in[0];
  const float* K = (const float*)d_in[1];
  const float* V = (const float*)d_in[2];
  float* O = (float*)d_out;
  dim3 grid(SS / QT, BB * HH);
  if (ws_size >= WS_NEED) {
    char* wsp = (char*)d_ws;
    prep_kv<<<4096, 256, 0, stream>>>(K, V, wsp);
    fused_attn_ws<<<grid, dim3(256), 0, stream>>>(Q, wsp, O);
  } else {
    fused_attn_fallback<<<grid, dim3(256), 0, stream>>>(Q, K, V, O);
  }
}